// Round 10
// baseline (398.157 us; speedup 1.0000x reference)
//
#include <hip/hip_runtime.h>
#include <stdint.h>

typedef __bf16 bf16_t;
typedef __bf16 bf16x8 __attribute__((ext_vector_type(8)));
typedef float f32x4 __attribute__((ext_vector_type(4)));
typedef uint32_t u32x4 __attribute__((ext_vector_type(4)));

#define N_NODES  50000
#define N_EDGES  400000
#define D_IN     512
#define D_HID    512
#define D_OUTD   256
#define M_PAD    50048   // 391 * 128 (GEMM M padded)
#define NB_SCAN  196     // ceil(50000/256)

// ---------- helpers ----------
__device__ __forceinline__ uint32_t f2bf_bits(float x){
    uint32_t u = __float_as_uint(x);
    return (u + 0x7fffu + ((u >> 16) & 1u)) >> 16;   // RNE
}
__device__ __forceinline__ void unpack8(uint4 v, float* f){
    f[0]=__uint_as_float(v.x<<16); f[1]=__uint_as_float(v.x & 0xffff0000u);
    f[2]=__uint_as_float(v.y<<16); f[3]=__uint_as_float(v.y & 0xffff0000u);
    f[4]=__uint_as_float(v.z<<16); f[5]=__uint_as_float(v.z & 0xffff0000u);
    f[6]=__uint_as_float(v.w<<16); f[7]=__uint_as_float(v.w & 0xffff0000u);
}
__device__ __forceinline__ void glds16(const bf16_t* g, bf16_t* l){
    __builtin_amdgcn_global_load_lds(
        (const __attribute__((address_space(1))) uint32_t*)g,
        (__attribute__((address_space(3))) uint32_t*)l, 16, 0, 0);
}

// ---------- tiny init (deg=1 self-loop) ----------
__global__ __launch_bounds__(256)
void k_init_deg(int* __restrict__ deg){
    int i = blockIdx.x*256 + threadIdx.x;
    if (i < N_NODES) deg[i] = 1;
}

// Both weight transposes + edge degree count in one launch.
// grid = 1568 blocks (401408 threads >= max(768*512, N_EDGES))
__global__ __launch_bounds__(256)
void conv_w_both(const float* __restrict__ W1, const float* __restrict__ W2,
                 bf16_t* __restrict__ W1t, bf16_t* __restrict__ W2t,
                 const int* __restrict__ ei, int* __restrict__ deg){
    const int idx = blockIdx.x * 256 + threadIdx.x;  // n*512 + k
    if (idx < N_EDGES) atomicAdd(&deg[ei[N_EDGES + idx]], 1);
    const int n = idx >> 9;
    const int k = idx & 511;
    if (n < 512) W1t[idx] = (bf16_t)W1[k * 512 + n];
    else if (n < 768) W2t[(n - 512) * 512 + k] = (bf16_t)W2[k * 256 + (n - 512)];
}

// ---------- CSR build (scan chain — proven) ----------
__global__ __launch_bounds__(256)
void k_scan_dinv(const int* __restrict__ deg, float* __restrict__ dinv,
                 int* __restrict__ part, int* __restrict__ bsum, int n){
    __shared__ int tmp[256];
    int i = blockIdx.x*256 + threadIdx.x;
    int d = (i < n) ? deg[i] : 1;
    if (i < n) dinv[i] = rsqrtf((float)d);
    int v = (i < n) ? (d - 1) : 0;
    tmp[threadIdx.x] = v;
    __syncthreads();
    for (int off = 1; off < 256; off <<= 1){
        int t = (threadIdx.x >= off) ? tmp[threadIdx.x - off] : 0;
        __syncthreads();
        tmp[threadIdx.x] += t;
        __syncthreads();
    }
    if (i < n) part[i] = tmp[threadIdx.x] - v;
    if (threadIdx.x == 255) bsum[blockIdx.x] = tmp[255];
}
__global__ __launch_bounds__(256)
void k_scan_bsum(const int* __restrict__ bsum, int* __restrict__ bsum2, int nb){
    __shared__ int tmp[256];
    int v = (threadIdx.x < nb) ? bsum[threadIdx.x] : 0;
    tmp[threadIdx.x] = v;
    __syncthreads();
    for (int off = 1; off < 256; off <<= 1){
        int t = (threadIdx.x >= off) ? tmp[threadIdx.x - off] : 0;
        __syncthreads();
        tmp[threadIdx.x] += t;
        __syncthreads();
    }
    if (threadIdx.x < nb) bsum2[threadIdx.x] = tmp[threadIdx.x] - v;
}
__global__ __launch_bounds__(256)
void k_finalize_rowptr(const int* __restrict__ part, const int* __restrict__ bsum2,
                       int* __restrict__ rowp, int* __restrict__ cursor, int n){
    int i = blockIdx.x*256 + threadIdx.x;
    if (i < n){ int r = part[i] + bsum2[blockIdx.x]; rowp[i] = r; cursor[i] = r; }
    if (i == 0) rowp[n] = N_EDGES;
}
__global__ __launch_bounds__(256)
void k_place(const int* __restrict__ ei, const float* __restrict__ dinv,
             int* __restrict__ cursor, int* __restrict__ csrc, float* __restrict__ cnorm){
    int e = blockIdx.x*256 + threadIdx.x;
    if (e < N_EDGES){
        int s = ei[e];
        int d = ei[N_EDGES + e];
        int p = atomicAdd(&cursor[d], 1);
        csrc[p]  = s;
        cnorm[p] = dinv[s] * dinv[d];
    }
}

// ---------- layer-1 fused GEMM: T[128-tile][512] = bf16(x) @ W1t^T ----------
// FULL-N tile 128x512, BK=32, 512 threads = 8 waves in 2x4 (each 64 rows x 128 cols,
// 4x8 MFMA 16x16x32). x (fp32) is read ONCE and converted during reg-staging --
// deletes the conv_x pass (153 MB) and halves gemm1's A traffic (traffic-bound,
// proven r9). B (W1t, 512 KB) stages via global_load_lds and lives in L2.
__global__ __launch_bounds__(512)
void gemm1_fused(const float* __restrict__ x, const bf16_t* __restrict__ W1t,
                 bf16_t* __restrict__ T)
{
    __shared__ bf16_t As[128*32];    // 8 KB
    __shared__ bf16_t Bs[512*32];    // 32 KB

    const int tid  = threadIdx.x;
    const int lane = tid & 63;
    const int wave = tid >> 6;        // 0..7
    const int wr = wave >> 2;         // 0..1 (row half)
    const int wc = wave & 3;          // 0..3 (128-col quarter)
    const int mBase = blockIdx.x * 128;

    // A staging (reg->cvt->LDS): thread t handles row t>>2, 8 cols at (t&3)*8
    const int arow = tid >> 2;
    const int acol = (tid & 3) << 3;
    const bool avalid = (mBase + arow) < N_NODES;   // pad rows stage zeros
    const float* Ag = x + (size_t)(mBase + arow) * 512 + acol;

    // B staging via global_load_lds: 4 calls, call c covers n-rows c*128..+127
    const bf16_t* Bg[4];
    #pragma unroll
    for (int c = 0; c < 4; ++c)
        Bg[c] = W1t + (size_t)(c*128 + arow) * 512 + acol;

    const int m16 = lane & 15;
    const int q   = lane >> 4;
    const bf16_t* aP = &As[(wr*64 + m16)*32 + q*8];
    const bf16_t* bP = &Bs[(wc*128 + m16)*32 + q*8];

    f32x4 acc[4][8] = {};

    for (int k0 = 0; k0 < 512; k0 += 32){
        #pragma unroll
        for (int c = 0; c < 4; ++c)
            glds16(Bg[c] + k0, &Bs[(size_t)(c*512 + tid) * 8]);
        uint4 aw = {0u, 0u, 0u, 0u};
        if (avalid){
            f32x4 v0 = __builtin_nontemporal_load((const f32x4*)(Ag + k0));
            f32x4 v1 = __builtin_nontemporal_load((const f32x4*)(Ag + k0 + 4));
            aw.x = f2bf_bits(v0.x) | (f2bf_bits(v0.y) << 16);
            aw.y = f2bf_bits(v0.z) | (f2bf_bits(v0.w) << 16);
            aw.z = f2bf_bits(v1.x) | (f2bf_bits(v1.y) << 16);
            aw.w = f2bf_bits(v1.z) | (f2bf_bits(v1.w) << 16);
        }
        *(uint4*)(&As[arow*32 + acol]) = aw;
        __syncthreads();           // drains lgkm (ds_write) + vmcnt (global_load_lds)
        bf16x8 a[4], b[8];
        #pragma unroll
        for (int t = 0; t < 4; ++t) a[t] = *(const bf16x8*)(aP + t*16*32);
        #pragma unroll
        for (int t = 0; t < 8; ++t) b[t] = *(const bf16x8*)(bP + t*16*32);
        #pragma unroll
        for (int i = 0; i < 4; ++i){
            #pragma unroll
            for (int j = 0; j < 8; ++j){
                acc[i][j] = __builtin_amdgcn_mfma_f32_16x16x32_bf16(a[i], b[j], acc[i][j], 0, 0, 0);
            }
        }
        __syncthreads();
    }

    // C/D layout: col = lane&15, row = q*4 + reg  [measured mapping]; N = 512
    #pragma unroll
    for (int i = 0; i < 4; ++i){
        const int row0 = mBase + wr*64 + i*16 + q*4;
        #pragma unroll
        for (int j = 0; j < 8; ++j){
            const int col = wc*128 + j*16 + m16;
            bf16_t* Cp = T + (size_t)row0 * 512 + col;
            #pragma unroll
            for (int r = 0; r < 4; ++r)
                Cp[(size_t)r * 512] = (bf16_t)acc[i][j][r];
        }
    }
}

// ---------- layer-2 GEMM: C[M_PAD][N] = A[M_PAD][K] @ Bt[N][K]^T ----------
// 128x256 tile, BK=32, 256 threads = 4 waves in 2x2 (r9 proven; N=256 -> A read once).
__global__ __launch_bounds__(256, 2)
void gemm_bf16_mfma(const bf16_t* __restrict__ A, const bf16_t* __restrict__ Bt,
                    bf16_t* __restrict__ C, int N, int K)
{
    __shared__ bf16_t As[128*32];   // [m][k], 8 KB
    __shared__ bf16_t Bs[256*32];   // [n][k], 16 KB

    const int tid  = threadIdx.x;
    const int lane = tid & 63;
    const int wave = tid >> 6;
    const int wr = wave >> 1;       // 0..1: row half
    const int wc = wave & 1;        // 0..1: col half (128 cols each)
    const int mBase = blockIdx.x * 128;
    const int nBase = blockIdx.y * 256;

    const int srow = tid >> 2;            // 0..63 within a 256-thread call
    const int scol = (tid & 3) << 3;
    const bf16_t* Ag0 = A  + (size_t)(mBase + srow) * K + scol;        // rows 0..63
    const bf16_t* Ag1 = A  + (size_t)(mBase + 64 + srow) * K + scol;   // rows 64..127
    const bf16_t* Bg[4];
    #pragma unroll
    for (int c = 0; c < 4; ++c)
        Bg[c] = Bt + (size_t)(nBase + c*64 + srow) * K + scol;

    const int m16 = lane & 15;
    const int q   = lane >> 4;
    const bf16_t* aP = &As[(wr*64 + m16)*32 + q*8];
    const bf16_t* bP = &Bs[(wc*128 + m16)*32 + q*8];

    f32x4 acc[4][8] = {};

    for (int k0 = 0; k0 < K; k0 += 32){
        glds16(Ag0 + k0, &As[(size_t)tid * 8]);
        glds16(Ag1 + k0, &As[(size_t)(256 + tid) * 8]);
        #pragma unroll
        for (int c = 0; c < 4; ++c)
            glds16(Bg[c] + k0, &Bs[(size_t)(c*256 + tid) * 8]);
        __syncthreads();           // drains vmcnt for global_load_lds
        bf16x8 a[4], b[8];
        #pragma unroll
        for (int t = 0; t < 4; ++t) a[t] = *(const bf16x8*)(aP + t*16*32);
        #pragma unroll
        for (int t = 0; t < 8; ++t) b[t] = *(const bf16x8*)(bP + t*16*32);
        #pragma unroll
        for (int i = 0; i < 4; ++i){
            #pragma unroll
            for (int j = 0; j < 8; ++j){
                acc[i][j] = __builtin_amdgcn_mfma_f32_16x16x32_bf16(a[i], b[j], acc[i][j], 0, 0, 0);
            }
        }
        __syncthreads();
    }

    // C/D layout: col = lane&15, row = q*4 + reg  [measured mapping]
    #pragma unroll
    for (int i = 0; i < 4; ++i){
        const int row0 = mBase + wr*64 + i*16 + q*4;
        #pragma unroll
        for (int j = 0; j < 8; ++j){
            const int col = nBase + wc*128 + j*16 + m16;
            bf16_t* Cp = C + (size_t)row0 * N + col;
            #pragma unroll
            for (int r = 0; r < 4; ++r)
                Cp[(size_t)r * N] = (bf16_t)acc[i][j][r];
        }
    }
}

// ---------- aggregation ----------
// layer 1: H[i] = relu(sum_e norm*T[src] + dinv[i]^2*T[i] + b), D=512, bf16 out.
// One wave per node, rotate pipeline (r8).
__global__ __launch_bounds__(256)
void agg_bias_relu_512(const bf16_t* __restrict__ T, const int* __restrict__ rowp,
                       const int* __restrict__ csrc, const float* __restrict__ cnorm,
                       const float* __restrict__ dinv, const float* __restrict__ bias,
                       bf16_t* __restrict__ H)
{
    const int gw   = (blockIdx.x * 256 + threadIdx.x) >> 6;
    const int lane = threadIdx.x & 63;
    if (gw >= N_NODES) return;
    const float di = dinv[gw];
    const uint4* Tr = (const uint4*)T;      // row s at uint4 index s*64
    float acc[8];
    {
        uint4 v = Tr[(size_t)gw * 64 + lane];
        float f[8]; unpack8(v, f);
        const float w = di * di;
        #pragma unroll
        for (int j = 0; j < 8; ++j) acc[j] = w * f[j];
    }
    int e = rowp[gw];
    const int e1 = rowp[gw + 1];

    if (e + 4 <= e1){
        uint4 v0, v1, v2, v3; float w0, w1, w2, w3;
        {
            const int s0 = csrc[e], s1 = csrc[e+1], s2 = csrc[e+2], s3 = csrc[e+3];
            w0 = cnorm[e]; w1 = cnorm[e+1]; w2 = cnorm[e+2]; w3 = cnorm[e+3];
            v0 = Tr[(size_t)s0 * 64 + lane];
            v1 = Tr[(size_t)s1 * 64 + lane];
            v2 = Tr[(size_t)s2 * 64 + lane];
            v3 = Tr[(size_t)s3 * 64 + lane];
        }
        e += 4;
        for (; e + 4 <= e1; e += 4){
            const int   t0 = csrc[e],   t1 = csrc[e+1], t2 = csrc[e+2], t3 = csrc[e+3];
            const float x0 = cnorm[e],  x1 = cnorm[e+1], x2 = cnorm[e+2], x3 = cnorm[e+3];
            uint4 n0 = Tr[(size_t)t0 * 64 + lane];
            uint4 n1 = Tr[(size_t)t1 * 64 + lane];
            uint4 n2 = Tr[(size_t)t2 * 64 + lane];
            uint4 n3 = Tr[(size_t)t3 * 64 + lane];
            float f[8];
            unpack8(v0, f);
            #pragma unroll
            for (int j = 0; j < 8; ++j) acc[j] += w0 * f[j];
            unpack8(v1, f);
            #pragma unroll
            for (int j = 0; j < 8; ++j) acc[j] += w1 * f[j];
            unpack8(v2, f);
            #pragma unroll
            for (int j = 0; j < 8; ++j) acc[j] += w2 * f[j];
            unpack8(v3, f);
            #pragma unroll
            for (int j = 0; j < 8; ++j) acc[j] += w3 * f[j];
            v0 = n0; v1 = n1; v2 = n2; v3 = n3;
            w0 = x0; w1 = x1; w2 = x2; w3 = x3;
        }
        float f[8];
        unpack8(v0, f);
        #pragma unroll
        for (int j = 0; j < 8; ++j) acc[j] += w0 * f[j];
        unpack8(v1, f);
        #pragma unroll
        for (int j = 0; j < 8; ++j) acc[j] += w1 * f[j];
        unpack8(v2, f);
        #pragma unroll
        for (int j = 0; j < 8; ++j) acc[j] += w2 * f[j];
        unpack8(v3, f);
        #pragma unroll
        for (int j = 0; j < 8; ++j) acc[j] += w3 * f[j];
    }
    for (; e < e1; ++e){
        const int   s = csrc[e];
        const float w = cnorm[e];
        uint4 v = Tr[(size_t)s * 64 + lane];
        float f[8]; unpack8(v, f);
        #pragma unroll
        for (int j = 0; j < 8; ++j) acc[j] += w * f[j];
    }
    const float4 b0 = ((const float4*)bias)[lane*2];
    const float4 b1 = ((const float4*)bias)[lane*2 + 1];
    float r[8] = {acc[0]+b0.x, acc[1]+b0.y, acc[2]+b0.z, acc[3]+b0.w,
                  acc[4]+b1.x, acc[5]+b1.y, acc[6]+b1.z, acc[7]+b1.w};
    u32x4 o;
    o.x = f2bf_bits(fmaxf(r[0],0.f)) | (f2bf_bits(fmaxf(r[1],0.f)) << 16);
    o.y = f2bf_bits(fmaxf(r[2],0.f)) | (f2bf_bits(fmaxf(r[3],0.f)) << 16);
    o.z = f2bf_bits(fmaxf(r[4],0.f)) | (f2bf_bits(fmaxf(r[5],0.f)) << 16);
    o.w = f2bf_bits(fmaxf(r[6],0.f)) | (f2bf_bits(fmaxf(r[7],0.f)) << 16);
    __builtin_nontemporal_store(o, ((u32x4*)(H + (size_t)gw * 512)) + lane);
}

// layer 2: out[i] = sum_e norm*T[src] + dinv[i]^2*T[i] + b, D=256, fp32 out.
// TWO nodes per wave (proven layout), x4 unroll + serial remainder.
__global__ __launch_bounds__(256)
void agg_bias_out_256(const bf16_t* __restrict__ T, const int* __restrict__ rowp,
                      const int* __restrict__ csrc, const float* __restrict__ cnorm,
                      const float* __restrict__ dinv, const float* __restrict__ bias,
                      float* __restrict__ out)
{
    const int wid  = (blockIdx.x * 256 + threadIdx.x) >> 6;
    const int half = (threadIdx.x >> 5) & 1;
    const int l32  = threadIdx.x & 31;
    const int node = wid * 2 + half;
    if (node >= N_NODES) return;
    const float di = dinv[node];
    float acc[8];
    {
        uint4 v = ((const uint4*)(T + (size_t)node * 256))[l32];
        float f[8]; unpack8(v, f);
        const float w = di * di;
        #pragma unroll
        for (int j = 0; j < 8; ++j) acc[j] = w * f[j];
    }
    int e = rowp[node];
    const int e1 = rowp[node + 1];
    for (; e + 4 <= e1; e += 4){
        const int   s0 = csrc[e],   s1 = csrc[e+1], s2 = csrc[e+2], s3 = csrc[e+3];
        const float w0 = cnorm[e],  w1 = cnorm[e+1], w2 = cnorm[e+2], w3 = cnorm[e+3];
        uint4 v0 = ((const uint4*)(T + (size_t)s0 * 256))[l32];
        uint4 v1 = ((const uint4*)(T + (size_t)s1 * 256))[l32];
        uint4 v2 = ((const uint4*)(T + (size_t)s2 * 256))[l32];
        uint4 v3 = ((const uint4*)(T + (size_t)s3 * 256))[l32];
        float f[8];
        unpack8(v0, f);
        #pragma unroll
        for (int j = 0; j < 8; ++j) acc[j] += w0 * f[j];
        unpack8(v1, f);
        #pragma unroll
        for (int j = 0; j < 8; ++j) acc[j] += w1 * f[j];
        unpack8(v2, f);
        #pragma unroll
        for (int j = 0; j < 8; ++j) acc[j] += w2 * f[j];
        unpack8(v3, f);
        #pragma unroll
        for (int j = 0; j < 8; ++j) acc[j] += w3 * f[j];
    }
    for (; e < e1; ++e){
        const int   s = csrc[e];
        const float w = cnorm[e];
        uint4 v = ((const uint4*)(T + (size_t)s * 256))[l32];
        float f[8]; unpack8(v, f);
        #pragma unroll
        for (int j = 0; j < 8; ++j) acc[j] += w * f[j];
    }
    const float4 b0 = ((const float4*)bias)[l32*2];
    const float4 b1 = ((const float4*)bias)[l32*2 + 1];
    f32x4 o0 = {acc[0]+b0.x, acc[1]+b0.y, acc[2]+b0.z, acc[3]+b0.w};
    f32x4 o1 = {acc[4]+b1.x, acc[5]+b1.y, acc[6]+b1.z, acc[7]+b1.w};
    __builtin_nontemporal_store(o0, ((f32x4*)(out + (size_t)node * 256)) + l32*2);
    __builtin_nontemporal_store(o1, ((f32x4*)(out + (size_t)node * 256)) + l32*2 + 1);
}

// ---------- host ----------
extern "C" void kernel_launch(void* const* d_in, const int* in_sizes, int n_in,
                              void* d_out, int out_size, void* d_ws, size_t ws_size,
                              hipStream_t stream)
{
    const float* x  = (const float*)d_in[0];
    const int*   ei = (const int*)d_in[1];     // [0..4e5)=src, [4e5..8e5)=dst
    const float* W1 = (const float*)d_in[2];
    const float* b1 = (const float*)d_in[3];
    const float* W2 = (const float*)d_in[4];
    const float* b2 = (const float*)d_in[5];
    float* out = (float*)d_out;

    // workspace carve (256B aligned)
    char* w = (char*)d_ws;
    auto alloc = [&](size_t bytes) -> char* {
        char* p = w; w += (bytes + 255) & ~(size_t)255; return p;
    };
    bf16_t* Hb    = (bf16_t*)alloc((size_t)M_PAD * 512 * 2);  // H (layer-1 output)
    bf16_t* T     = (bf16_t*)alloc((size_t)M_PAD * 512 * 2);  // T1, later reused as T2
    bf16_t* W1t   = (bf16_t*)alloc(512 * 512 * 2);
    bf16_t* W2t   = (bf16_t*)alloc(256 * 512 * 2);
    int*    deg   = (int*)  alloc(N_NODES * 4);
    float*  dinv  = (float*)alloc(N_NODES * 4);
    int*    rowp  = (int*)  alloc((N_NODES + 1) * 4);
    int*    cursor= (int*)  alloc(N_NODES * 4);
    int*    part  = (int*)  alloc(N_NODES * 4);
    int*    bsum  = (int*)  alloc(NB_SCAN * 4);
    int*    bsum2 = (int*)  alloc(NB_SCAN * 4);
    int*    csrc  = (int*)  alloc(N_EDGES * 4);
    float*  cnorm = (float*)alloc(N_EDGES * 4);

    // deg init, then weight transposes + edge degree count
    k_init_deg<<<NB_SCAN, 256, 0, stream>>>(deg);
    conv_w_both<<<1568, 256, 0, stream>>>(W1, W2, W1t, W2t, ei, deg);

    // CSR build (scan chain — proven)
    k_scan_dinv<<<NB_SCAN, 256, 0, stream>>>(deg, dinv, part, bsum, N_NODES);
    k_scan_bsum <<<1, 256, 0, stream>>>(bsum, bsum2, NB_SCAN);
    k_finalize_rowptr<<<NB_SCAN, 256, 0, stream>>>(part, bsum2, rowp, cursor, N_NODES);
    k_place   <<<(N_EDGES+255)/256, 256, 0, stream>>>(ei, dinv, cursor, csrc, cnorm);

    // layer 1: T1 = bf16(x) @ W1 (fused conversion, full-N tile, x read ONCE);
    //          H = relu(agg(T1) + b1)
    gemm1_fused<<<M_PAD/128, 512, 0, stream>>>(x, W1t, T);
    agg_bias_relu_512<<<(N_NODES+3)/4, 256, 0, stream>>>(T, rowp, csrc, cnorm, dinv, b1, Hb);

    // layer 2: T2 = H @ W2 ; out = agg(T2) + b2        (T2 reuses T buffer)
    gemm_bf16_mfma<<<dim3(M_PAD/128, 256/256), 256, 0, stream>>>(Hb, W2t, T, 256, 512);
    agg_bias_out_256<<<(25000+3)/4, 256, 0, stream>>>(T, rowp, csrc, cnorm, dinv, b2, out);
}